// Round 2
// baseline (312.204 us; speedup 1.0000x reference)
//
#include <hip/hip_runtime.h>
#include <math.h>

#define Bn 64
#define In 2048
#define On 2048
#define Sn 10
#define Cn 512

#define OT 4                 // o's per block
#define KSPLIT 4
#define KRANGE (In / KSPLIT) // 512
#define KT 128               // K tile per stage
#define NSTG (KRANGE / KT)   // 4
#define LROW 136             // KT + 8 pad (bf16 elems)
#define SLOT 12              // padded per-(b,o) partial slots: 10 dendrite + 1 syn + 1 pad

typedef short short8 __attribute__((ext_vector_type(8)));
typedef float f32x4 __attribute__((ext_vector_type(4)));
typedef unsigned short ushort4v __attribute__((ext_vector_type(4)));

__device__ __forceinline__ unsigned short f2bf(float f) {
    union { float f; unsigned u; } v; v.f = f;
    unsigned r = (v.u + 0x7FFFu + ((v.u >> 16) & 1u)) >> 16;  // RNE
    return (unsigned short)r;
}

// blocks 0..63: ctx_signal[b] = mean(context[b,:]); blocks 64..575: x -> bf16
__global__ void prep_kernel(const float* __restrict__ x,
                            const float* __restrict__ ctx,
                            float* __restrict__ ws_ctx,
                            unsigned short* __restrict__ ws_xbf) {
    const int b = blockIdx.x;
    const int t = threadIdx.x;
    if (b < Bn) {
        __shared__ float red[256];
        red[t] = ctx[b * Cn + t] + ctx[b * Cn + t + 256];
        __syncthreads();
        for (int off = 128; off > 0; off >>= 1) {
            if (t < off) red[t] += red[t + off];
            __syncthreads();
        }
        if (t == 0) ws_ctx[b] = red[0] * (1.0f / (float)Cn);
    } else {
        int idx = (b - Bn) * 256 + t;
        ws_xbf[idx] = f2bf(x[idx]);
    }
}

// mean_astro[o] = mean_b( sig(ctx_mean[b]*aact[o]) * (sig > athr[o]) )
__global__ void mastro_kernel(const float* __restrict__ aact,
                              const float* __restrict__ athr,
                              const float* __restrict__ ws_ctx,
                              float* __restrict__ ws_mastro) {
    const int o = blockIdx.x * 256 + threadIdx.x;
    const float aa = aact[o], th = athr[o];
    float sum = 0.0f;
    for (int b = 0; b < Bn; ++b) {
        float sg = 1.0f / (1.0f + expf(-ws_ctx[b] * aa));
        if (sg > th) sum += sg;
    }
    ws_mastro[o] = sum * (1.0f / (float)Bn);
}

// Per block: 4 o's x one K-split range (512). Writes raw partial sums to P.
__global__ __launch_bounds__(256, 8)
void main_kernel(const unsigned short* __restrict__ xbf,
                 const float* __restrict__ wgt,
                 const float* __restrict__ cst,
                 const float* __restrict__ seg,
                 const float* __restrict__ prn,
                 float* __restrict__ P) {
    __shared__ __align__(16) unsigned short Blds[48 * LROW];

    const int t = threadIdx.x;
    const int grp = blockIdx.x >> 2;       // 512 o-groups
    const int ks  = blockIdx.x & 3;        // k-split index
    const int o0 = grp * OT;
    const int ib = ks * KRANGE;
    const int w = t >> 6, l = t & 63;
    const int l15 = l & 15, q = l >> 4;
    const float pthr = prn[0];

    // zero pad rows 44..47 once (never rewritten; visible after first barrier)
    for (int idx = t; idx < 4 * LROW; idx += 256) Blds[44 * LROW + idx] = 0;

    f32x4 acc[3];
#pragma unroll
    for (int n = 0; n < 3; ++n) acc[n] = (f32x4){0.f, 0.f, 0.f, 0.f};

    const float* segw = seg + ((size_t)(o0 + w) * In) * Sn;  // wave w -> o0+w

    for (int is = 0; is < NSTG; ++is) {
        const int i0 = ib + is * KT;

        // ---- coalesced seg load: 1280 contiguous floats per wave ----
        unsigned psv[10];  // packed bf16 pairs
        {
            const float* sp = segw + (size_t)i0 * Sn;
#pragma unroll
            for (int c = 0; c < 10; ++c) {
                float2 f2 = *(const float2*)(sp + c * 128 + 2 * l);
                psv[c] = (unsigned)f2bf(f2.x) | ((unsigned)f2bf(f2.y) << 16);
            }
        }
        // ---- synaptic weights (wave 0): 4 o x 128 k of wgt & cst ----
        ushort4v ew[2];
        if (w == 0) {
#pragma unroll
            for (int i = 0; i < 2; ++i) {
                const int o_l = i * 2 + (l >> 5);
                const int col = (l & 31) * 4;
                f32x4 wv = *(const f32x4*)(wgt + (size_t)(o0 + o_l) * In + i0 + col);
                f32x4 cv = *(const f32x4*)(cst + (size_t)(o0 + o_l) * In + i0 + col);
#pragma unroll
                for (int j = 0; j < 4; ++j) {
                    float wj = wv[j];
                    ew[i][j] = f2bf((__builtin_fabsf(wj) * cv[j] > pthr) ? wj : 0.0f);
                }
            }
        }

        __syncthreads();   // previous compute done; safe to overwrite LDS

        // ---- scatter to LDS: row = o_local*10 + s, col = i (bf16) ----
#pragma unroll
        for (int c = 0; c < 10; ++c) {
            unsigned j = (unsigned)(c * 128 + 2 * l);
            unsigned ii = j / 10u;
            unsigned s = j - ii * 10u;       // even; s+1 <= 9, same ii
            unsigned short* bp = &Blds[(w * Sn + s) * LROW + ii];
            bp[0] = (unsigned short)psv[c];
            bp[LROW] = (unsigned short)(psv[c] >> 16);
        }
        if (w == 0) {
#pragma unroll
            for (int i = 0; i < 2; ++i) {
                const int o_l = i * 2 + (l >> 5);
                const int col = (l & 31) * 4;
                *(ushort4v*)&Blds[(40 + o_l) * LROW + col] = ew[i];
            }
        }
        __syncthreads();

        // ---- MFMA: A-fragments direct from global (L2-resident x) ----
        const unsigned short* xrow = xbf + (size_t)(w * 16 + l15) * In + i0 + q * 8;
#pragma unroll
        for (int kk = 0; kk < KT; kk += 32) {
            short8 a  = *(const short8*)(xrow + kk);
            short8 b0 = *(const short8*)&Blds[(0  + l15) * LROW + q * 8 + kk];
            short8 b1 = *(const short8*)&Blds[(16 + l15) * LROW + q * 8 + kk];
            short8 b2 = *(const short8*)&Blds[(32 + l15) * LROW + q * 8 + kk];
            acc[0] = __builtin_amdgcn_mfma_f32_16x16x32_bf16(a, b0, acc[0], 0, 0, 0);
            acc[1] = __builtin_amdgcn_mfma_f32_16x16x32_bf16(a, b1, acc[1], 0, 0, 0);
            acc[2] = __builtin_amdgcn_mfma_f32_16x16x32_bf16(a, b2, acc[2], 0, 0, 0);
        }
    }

    // ---- write raw partials: P[ks][b][o][SLOT] ----
#pragma unroll
    for (int nt = 0; nt < 3; ++nt) {
        const unsigned n = nt * 16 + l15;
#pragma unroll
        for (int r = 0; r < 4; ++r) {
            const int m = w * 16 + q * 4 + r;             // batch index
            const size_t base = (((size_t)ks * Bn + m) * On + o0) * SLOT;
            if (n < 40u) {
                unsigned ol = n / 10u, s = n - ol * 10u;
                P[base + ol * SLOT + s] = acc[nt][r];
            } else if (n < 44u) {
                P[base + (n - 40u) * SLOT + 10] = acc[nt][r];
            }
        }
    }
}

// Combine k-splits, apply gating/relu/astro/bias/relu.
__global__ void finalize_kernel(const float* __restrict__ P,
                                const float* __restrict__ gates,
                                const float* __restrict__ bias,
                                const float* __restrict__ ws_mastro,
                                float* __restrict__ out) {
    const int t = threadIdx.x;
    const int o = (blockIdx.x & 31) * 64 + (t & 63);
    const int b = (blockIdx.x >> 5) * 4 + (t >> 6);
    f32x4 v0 = {0.f, 0.f, 0.f, 0.f}, v1 = v0, v2 = v0;
#pragma unroll
    for (int ks = 0; ks < KSPLIT; ++ks) {
        const f32x4* p = (const f32x4*)(P + (((size_t)ks * Bn + b) * On + o) * SLOT);
        v0 += p[0]; v1 += p[1]; v2 += p[2];
    }
    float d[12];
#pragma unroll
    for (int j = 0; j < 4; ++j) { d[j] = v0[j]; d[4 + j] = v1[j]; d[8 + j] = v2[j]; }
    float dend = 0.0f;
#pragma unroll
    for (int s = 0; s < Sn; ++s) {
        float g = 1.0f / (1.0f + expf(-gates[o * Sn + s]));
        float r = d[s] > 0.0f ? d[s] : 0.0f;
        dend += r * g;
    }
    float val = d[10] * ws_mastro[o] + bias[o] + dend;
    out[(size_t)b * On + o] = val > 0.0f ? val : 0.0f;
}

extern "C" void kernel_launch(void* const* d_in, const int* in_sizes, int n_in,
                              void* d_out, int out_size, void* d_ws, size_t ws_size,
                              hipStream_t stream) {
    (void)in_sizes; (void)n_in; (void)out_size; (void)ws_size;
    const float* x    = (const float*)d_in[0];
    const float* ctx  = (const float*)d_in[1];
    // d_in[2] prev_activation: unused by the reference
    const float* wgt  = (const float*)d_in[3];
    const float* bias = (const float*)d_in[4];
    const float* aact = (const float*)d_in[5];
    const float* athr = (const float*)d_in[6];
    const float* seg  = (const float*)d_in[7];
    const float* gat  = (const float*)d_in[8];
    const float* cst  = (const float*)d_in[9];
    const float* prn  = (const float*)d_in[10];
    float* out = (float*)d_out;

    float* ws_ctx = (float*)d_ws;                                        // 64 f32
    unsigned short* ws_xbf = (unsigned short*)((char*)d_ws + 256);       // 64x2048 bf16
    float* ws_mastro = (float*)((char*)d_ws + 262400);                   // 2048 f32
    float* ws_P = (float*)((char*)d_ws + 270592);                        // 4*64*2048*12 f32 (~25 MB)

    prep_kernel<<<Bn + (Bn * In) / 256, 256, 0, stream>>>(x, ctx, ws_ctx, ws_xbf);
    mastro_kernel<<<On / 256, 256, 0, stream>>>(aact, athr, ws_ctx, ws_mastro);
    main_kernel<<<(On / OT) * KSPLIT, 256, 0, stream>>>(ws_xbf, wgt, cst, seg, prn, ws_P);
    finalize_kernel<<<(On / 64) * (Bn / 4), 256, 0, stream>>>(ws_P, gat, bias, ws_mastro, out);
}

// Round 3
// 301.159 us; speedup vs baseline: 1.0367x; 1.0367x over previous
//
#include <hip/hip_runtime.h>
#include <math.h>

#define Bn 64
#define In 2048
#define On 2048
#define Sn 10
#define Cn 512

#define OT 4                 // o's per block
#define KSPLIT 4
#define KRANGE (In / KSPLIT) // 512
#define KT 64                // K tile per stage
#define NSTG (KRANGE / KT)   // 8
#define LROW 72              // KT + 8 pad (bf16 elems), 144B row = 16B aligned
#define SLOT 12              // per-(b,o) partial slots: 10 dendrite + 1 syn + 1 pad

typedef short short8 __attribute__((ext_vector_type(8)));
typedef float f32x4 __attribute__((ext_vector_type(4)));

__device__ __forceinline__ unsigned short f2bf(float f) {
    union { float f; unsigned u; } v; v.f = f;
    unsigned r = (v.u + 0x7FFFu + ((v.u >> 16) & 1u)) >> 16;  // RNE
    return (unsigned short)r;
}

// blocks 0..63: ctx_signal[b] = mean(context[b,:]); blocks 64..575: x -> bf16
__global__ void prep_kernel(const float* __restrict__ x,
                            const float* __restrict__ ctx,
                            float* __restrict__ ws_ctx,
                            unsigned short* __restrict__ ws_xbf) {
    const int b = blockIdx.x;
    const int t = threadIdx.x;
    if (b < Bn) {
        __shared__ float red[256];
        red[t] = ctx[b * Cn + t] + ctx[b * Cn + t + 256];
        __syncthreads();
        for (int off = 128; off > 0; off >>= 1) {
            if (t < off) red[t] += red[t + off];
            __syncthreads();
        }
        if (t == 0) ws_ctx[b] = red[0] * (1.0f / (float)Cn);
    } else {
        int idx = (b - Bn) * 256 + t;
        ws_xbf[idx] = f2bf(x[idx]);
    }
}

// mean_astro[o] = mean_b( sig(ctx_mean[b]*aact[o]) * (sig > athr[o]) )
__global__ void mastro_kernel(const float* __restrict__ aact,
                              const float* __restrict__ athr,
                              const float* __restrict__ ws_ctx,
                              float* __restrict__ ws_mastro) {
    const int o = blockIdx.x * 256 + threadIdx.x;
    const float aa = aact[o], th = athr[o];
    float sum = 0.0f;
    for (int b = 0; b < Bn; ++b) {
        float sg = 1.0f / (1.0f + expf(-ws_ctx[b] * aa));
        if (sg > th) sum += sg;
    }
    ws_mastro[o] = sum * (1.0f / (float)Bn);
}

// Per block: 4 o's x one K-split range (512), software-pipelined.
__global__ __launch_bounds__(256, 8)
void main_kernel(const unsigned short* __restrict__ xbf,
                 const float* __restrict__ wgt,
                 const float* __restrict__ cst,
                 const float* __restrict__ seg,
                 const float* __restrict__ prn,
                 float* __restrict__ P) {
    __shared__ __align__(16) unsigned short Blds[2][48 * LROW];

    const int t = threadIdx.x;
    const int grp = blockIdx.x >> 2;       // 512 o-groups
    const int ks  = blockIdx.x & 3;        // k-split index
    const int o0 = grp * OT;
    const int ib = ks * KRANGE;
    const int w = t >> 6, l = t & 63;
    const int l15 = l & 15, q = l >> 4;
    const float pthr = prn[0];

    // zero pad rows 44..47 of both buffers (never rewritten)
    for (int idx = t; idx < 4 * LROW; idx += 256) {
        Blds[0][44 * LROW + idx] = 0;
        Blds[1][44 * LROW + idx] = 0;
    }

    // scatter divmod seed: j = c*128 + 2l, ii=j/10, s=j%10 (s always even)
    const int ii0 = (2 * l) / 10;
    const int s0  = (2 * l) % 10;

    // ---- prefetch register state (one stage ahead) ----
    float2 sv[5];     // seg chunk: wave w -> output o0+w, 640 floats/wave/stage
    float wv, cv;     // synaptic weight + connection strength (1 per lane)

    const float* segw = seg + (size_t)(o0 + w) * In * Sn;

    auto load_stage = [&](int is) {
        const float* sp = segw + (size_t)(ib + is * KT) * Sn + 2 * l;
#pragma unroll
        for (int c = 0; c < 5; ++c) sv[c] = *(const float2*)(sp + c * 128);
        wv = wgt[(size_t)(o0 + w) * In + ib + is * KT + l];
        cv = cst[(size_t)(o0 + w) * In + ib + is * KT + l];
    };

    auto store_stage = [&](int bb) {
        int ii = ii0, s = s0;
#pragma unroll
        for (int c = 0; c < 5; ++c) {
            unsigned short* bp = &Blds[bb][(w * Sn + s) * LROW + ii];
            bp[0]    = f2bf(sv[c].x);     // (ii, s)
            bp[LROW] = f2bf(sv[c].y);     // (ii, s+1): s even -> same ii
            s += 8; ii += 12;
            if (s >= 10) { s -= 10; ++ii; }
        }
        float e = (__builtin_fabsf(wv) * cv > pthr) ? wv : 0.0f;
        Blds[bb][(40 + w) * LROW + l] = f2bf(e);
    };

    f32x4 acc[3];
#pragma unroll
    for (int n = 0; n < 3; ++n) acc[n] = (f32x4){0.f, 0.f, 0.f, 0.f};

    auto compute = [&](int bb, int is) {
        const unsigned short* xrow =
            xbf + (size_t)(w * 16 + l15) * In + ib + is * KT + q * 8;
#pragma unroll
        for (int kk = 0; kk < KT; kk += 32) {
            short8 a  = *(const short8*)(xrow + kk);
            short8 b0 = *(const short8*)&Blds[bb][(0  + l15) * LROW + q * 8 + kk];
            short8 b1 = *(const short8*)&Blds[bb][(16 + l15) * LROW + q * 8 + kk];
            short8 b2 = *(const short8*)&Blds[bb][(32 + l15) * LROW + q * 8 + kk];
            acc[0] = __builtin_amdgcn_mfma_f32_16x16x32_bf16(a, b0, acc[0], 0, 0, 0);
            acc[1] = __builtin_amdgcn_mfma_f32_16x16x32_bf16(a, b1, acc[1], 0, 0, 0);
            acc[2] = __builtin_amdgcn_mfma_f32_16x16x32_bf16(a, b2, acc[2], 0, 0, 0);
        }
    };

    // ---- pipelined K loop: loads for is+2 in flight during stage is ----
    load_stage(0);
    store_stage(0);            // only unhidden latency: first stage
    load_stage(1);
    __syncthreads();
    for (int is = 0; is < NSTG; ++is) {
        compute(is & 1, is);
        if (is + 1 < NSTG) {
            store_stage((is + 1) & 1);      // consumes regs loaded one iter ago
            if (is + 2 < NSTG) load_stage(is + 2);
        }
        __syncthreads();
    }

    // ---- epilogue: wave-local LDS transpose -> coalesced dwordx4 stores ----
    // lane holds acc[nt][r] at (m = w*16 + q*4 + r, n = nt*16 + l15)
    float* scratch = (float*)&Blds[0][0] + w * (16 * 48);
#pragma unroll
    for (int nt = 0; nt < 3; ++nt) {
        const int n = nt * 16 + l15;
        if (n < 44) {
#pragma unroll
            for (int r = 0; r < 4; ++r)
                scratch[(q * 4 + r) * 48 + n] = acc[nt][r];
        }
    }
    __syncthreads();
    {
        const int mloc = l >> 2, ol = l & 3;
        const float* srow = (const float*)&Blds[0][0] + w * (16 * 48) + mloc * 48;
        float d[10];
#pragma unroll
        for (int s = 0; s < 10; ++s) d[s] = srow[ol * 10 + s];
        const float syn = srow[40 + ol];
        f32x4 p0 = {d[0], d[1], d[2], d[3]};
        f32x4 p1 = {d[4], d[5], d[6], d[7]};
        f32x4 p2 = {d[8], d[9], syn, 0.0f};
        const int m = w * 16 + mloc;
        float* pp = P + (((size_t)ks * Bn + m) * On + o0 + ol) * SLOT;
        *(f32x4*)(pp)     = p0;
        *(f32x4*)(pp + 4) = p1;
        *(f32x4*)(pp + 8) = p2;
    }
}

// Combine k-splits, apply gating/relu/astro/bias/relu.
__global__ void finalize_kernel(const float* __restrict__ P,
                                const float* __restrict__ gates,
                                const float* __restrict__ bias,
                                const float* __restrict__ ws_mastro,
                                float* __restrict__ out) {
    const int t = threadIdx.x;
    const int o = (blockIdx.x & 31) * 64 + (t & 63);
    const int b = (blockIdx.x >> 5) * 4 + (t >> 6);
    f32x4 v0 = {0.f, 0.f, 0.f, 0.f}, v1 = v0, v2 = v0;
#pragma unroll
    for (int ks = 0; ks < KSPLIT; ++ks) {
        const f32x4* p = (const f32x4*)(P + (((size_t)ks * Bn + b) * On + o) * SLOT);
        v0 += p[0]; v1 += p[1]; v2 += p[2];
    }
    float d[12];
#pragma unroll
    for (int j = 0; j < 4; ++j) { d[j] = v0[j]; d[4 + j] = v1[j]; d[8 + j] = v2[j]; }
    float dend = 0.0f;
#pragma unroll
    for (int s = 0; s < Sn; ++s) {
        float g = 1.0f / (1.0f + expf(-gates[o * Sn + s]));
        float r = d[s] > 0.0f ? d[s] : 0.0f;
        dend += r * g;
    }
    float val = d[10] * ws_mastro[o] + bias[o] + dend;
    out[(size_t)b * On + o] = val > 0.0f ? val : 0.0f;
}

extern "C" void kernel_launch(void* const* d_in, const int* in_sizes, int n_in,
                              void* d_out, int out_size, void* d_ws, size_t ws_size,
                              hipStream_t stream) {
    (void)in_sizes; (void)n_in; (void)out_size; (void)ws_size;
    const float* x    = (const float*)d_in[0];
    const float* ctx  = (const float*)d_in[1];
    // d_in[2] prev_activation: unused by the reference
    const float* wgt  = (const float*)d_in[3];
    const float* bias = (const float*)d_in[4];
    const float* aact = (const float*)d_in[5];
    const float* athr = (const float*)d_in[6];
    const float* seg  = (const float*)d_in[7];
    const float* gat  = (const float*)d_in[8];
    const float* cst  = (const float*)d_in[9];
    const float* prn  = (const float*)d_in[10];
    float* out = (float*)d_out;

    float* ws_ctx = (float*)d_ws;                                        // 64 f32
    unsigned short* ws_xbf = (unsigned short*)((char*)d_ws + 256);       // 64x2048 bf16
    float* ws_mastro = (float*)((char*)d_ws + 262400);                   // 2048 f32
    float* ws_P = (float*)((char*)d_ws + 270592);                        // 4*64*2048*12 f32 (~25 MB)

    prep_kernel<<<Bn + (Bn * In) / 256, 256, 0, stream>>>(x, ctx, ws_ctx, ws_xbf);
    mastro_kernel<<<On / 256, 256, 0, stream>>>(aact, athr, ws_ctx, ws_mastro);
    main_kernel<<<(On / OT) * KSPLIT, 256, 0, stream>>>(ws_xbf, wgt, cst, seg, prn, ws_P);
    finalize_kernel<<<(On / 64) * (Bn / 4), 256, 0, stream>>>(ws_P, gat, bias, ws_mastro, out);
}

// Round 4
// 300.064 us; speedup vs baseline: 1.0405x; 1.0037x over previous
//
#include <hip/hip_runtime.h>
#include <math.h>

#define Bn 64
#define In 2048
#define On 2048
#define Sn 10
#define Cn 512

#define KSPLIT 4
#define KRANGE (In / KSPLIT) // 512
#define KT 64                // K tile per stage
#define NSTG (KRANGE / KT)   // 8
#define LROW 72              // KT + 8 pad (bf16 elems), 144 B rows
#define SROW 50              // epilogue scratch row stride (f32)
#define SLOT 12              // per-(o,b) partial slots: 10 dendrite + 1 syn + 1 pad

typedef short short8 __attribute__((ext_vector_type(8)));
typedef float f32x4 __attribute__((ext_vector_type(4)));

__device__ __forceinline__ unsigned short f2bf(float f) {
    union { float f; unsigned u; } v; v.f = f;
    unsigned r = (v.u + 0x7FFFu + ((v.u >> 16) & 1u)) >> 16;  // RNE
    return (unsigned short)r;
}

// blocks 0..63: ctx_signal[b] = mean(context[b,:]); blocks 64..575: x -> bf16
__global__ void prep_kernel(const float* __restrict__ x,
                            const float* __restrict__ ctx,
                            float* __restrict__ ws_ctx,
                            unsigned short* __restrict__ ws_xbf) {
    const int b = blockIdx.x;
    const int t = threadIdx.x;
    if (b < Bn) {
        __shared__ float red[256];
        red[t] = ctx[b * Cn + t] + ctx[b * Cn + t + 256];
        __syncthreads();
        for (int off = 128; off > 0; off >>= 1) {
            if (t < off) red[t] += red[t + off];
            __syncthreads();
        }
        if (t == 0) ws_ctx[b] = red[0] * (1.0f / (float)Cn);
    } else {
        int idx = (b - Bn) * 256 + t;
        ws_xbf[idx] = f2bf(x[idx]);
    }
}

// mean_astro[o] = mean_b( sig(ctx_mean[b]*aact[o]) * (sig > athr[o]) )
__global__ void mastro_kernel(const float* __restrict__ aact,
                              const float* __restrict__ athr,
                              const float* __restrict__ ws_ctx,
                              float* __restrict__ ws_mastro) {
    const int o = blockIdx.x * 256 + threadIdx.x;
    const float aa = aact[o], th = athr[o];
    float sum = 0.0f;
    for (int b = 0; b < Bn; ++b) {
        float sg = 1.0f / (1.0f + expf(-ws_ctx[b] * aa));
        if (sg > th) sum += sg;
    }
    ws_mastro[o] = sum * (1.0f / (float)Bn);
}

// ONE WAVE per block. No __syncthreads anywhere -> no vmcnt(0) barrier drains.
// Wave owns 4 o's x one K-quarter; covers all 64 batch rows (4 m-frags).
__global__ __launch_bounds__(64, 2)
void main_kernel(const unsigned short* __restrict__ xbf,
                 const float* __restrict__ wgt,
                 const float* __restrict__ cst,
                 const float* __restrict__ seg,
                 const float* __restrict__ prn,
                 float* __restrict__ P) {
    __shared__ __align__(16) unsigned short Blds[2][48 * LROW];  // 13824 B

    const int l = threadIdx.x;
    const int grp = blockIdx.x >> 2;       // 512 o-groups
    const int ks  = blockIdx.x & 3;        // k-split index
    const int o0 = grp * 4;
    const int ib = ks * KRANGE;
    const int l15 = l & 15, q = l >> 4;
    const float pthr = prn[0];

    // zero pad rows 44..47 of both buffers (single wave: lgkm ordering suffices)
    for (int idx = l; idx < 4 * LROW; idx += 64) {
        Blds[0][44 * LROW + idx] = 0;
        Blds[1][44 * LROW + idx] = 0;
    }

    // scatter divmod seed: j = c*128 + 2l, ii=j/10, s=j%10 (s always even)
    const int ii0 = (2 * l) / 10;
    const int s0  = (2 * l) % 10;

    float2 sv[4][5];          // seg stage: 4 o's x 640 floats (lane: 10 each)
    float wv[4], cv[4];

    auto load_stage = [&](int is) {
        const int k0 = ib + is * KT;
#pragma unroll
        for (int oo = 0; oo < 4; ++oo) {
            const float* sp = seg + ((size_t)(o0 + oo) * In + k0) * Sn + 2 * l;
#pragma unroll
            for (int c = 0; c < 5; ++c) sv[oo][c] = *(const float2*)(sp + c * 128);
            wv[oo] = wgt[(size_t)(o0 + oo) * In + k0 + l];
            cv[oo] = cst[(size_t)(o0 + oo) * In + k0 + l];
        }
    };

    auto store_stage = [&](int bb) {
#pragma unroll
        for (int oo = 0; oo < 4; ++oo) {
            int ii = ii0, s = s0;
#pragma unroll
            for (int c = 0; c < 5; ++c) {
                unsigned short* bp = &Blds[bb][(oo * 10 + s) * LROW + ii];
                bp[0]    = f2bf(sv[oo][c].x);   // (row oo*10+s,   col ii)
                bp[LROW] = f2bf(sv[oo][c].y);   // (row oo*10+s+1, col ii)
                s += 8; ii += 12;
                if (s >= 10) { s -= 10; ++ii; }
            }
            float e = (__builtin_fabsf(wv[oo]) * cv[oo] > pthr) ? wv[oo] : 0.0f;
            Blds[bb][(40 + oo) * LROW + l] = f2bf(e);
        }
    };

    f32x4 acc[12];            // [mt][nt] -> acc[mt*3+nt]
#pragma unroll
    for (int n = 0; n < 12; ++n) acc[n] = (f32x4){0.f, 0.f, 0.f, 0.f};

    auto compute = [&](int bb, int is) {
        const int k0 = ib + is * KT;
#pragma unroll
        for (int kk = 0; kk < KT; kk += 32) {
            short8 a[4];
#pragma unroll
            for (int mt = 0; mt < 4; ++mt)
                a[mt] = *(const short8*)(xbf + (size_t)(mt * 16 + l15) * In + k0 + q * 8 + kk);
            short8 b0 = *(const short8*)&Blds[bb][(0  + l15) * LROW + q * 8 + kk];
            short8 b1 = *(const short8*)&Blds[bb][(16 + l15) * LROW + q * 8 + kk];
            short8 b2 = *(const short8*)&Blds[bb][(32 + l15) * LROW + q * 8 + kk];
#pragma unroll
            for (int mt = 0; mt < 4; ++mt) {
                acc[mt * 3 + 0] = __builtin_amdgcn_mfma_f32_16x16x32_bf16(a[mt], b0, acc[mt * 3 + 0], 0, 0, 0);
                acc[mt * 3 + 1] = __builtin_amdgcn_mfma_f32_16x16x32_bf16(a[mt], b1, acc[mt * 3 + 1], 0, 0, 0);
                acc[mt * 3 + 2] = __builtin_amdgcn_mfma_f32_16x16x32_bf16(a[mt], b2, acc[mt * 3 + 2], 0, 0, 0);
            }
        }
    };

    // ---- barrier-free pipelined K loop (per-wave vmcnt only) ----
    load_stage(0);
    store_stage(0);
    load_stage(1);
    for (int is = 0; is < NSTG; ++is) {
        compute(is & 1, is);
        if (is + 1 < NSTG) {
            store_stage((is + 1) & 1);      // waits on regs loaded one iter ago
            if (is + 2 < NSTG) load_stage(is + 2);
        }
    }

    // ---- epilogue: wave-local LDS transpose -> contiguous P stores ----
    // lane holds acc[mt*3+nt][r] at (m = mt*16 + q*4 + r, n = nt*16 + l15)
    float* scratch = (float*)&Blds[0][0];
#pragma unroll
    for (int mt = 0; mt < 4; ++mt)
#pragma unroll
        for (int nt = 0; nt < 3; ++nt) {
            const int n = nt * 16 + l15;
            if (n < 44) {
#pragma unroll
                for (int r = 0; r < 4; ++r)
                    scratch[(mt * 16 + q * 4 + r) * SROW + n] = acc[mt * 3 + nt][r];
            }
        }
    // same wave: compiler orders LDS write->read with lgkmcnt
    const float* srow = scratch + l * SROW;   // lane l -> batch row l
#pragma unroll
    for (int ol = 0; ol < 4; ++ol) {
        float d[10];
#pragma unroll
        for (int s = 0; s < 10; ++s) d[s] = srow[ol * 10 + s];
        const float syn = srow[40 + ol];
        f32x4 p0 = {d[0], d[1], d[2], d[3]};
        f32x4 p1 = {d[4], d[5], d[6], d[7]};
        f32x4 p2 = {d[8], d[9], syn, 0.0f};
        // P layout: [ks][o][b][SLOT] -> lanes (b) contiguous, 48 B apart
        float* pp = P + (((size_t)ks * On + o0 + ol) * Bn + l) * SLOT;
        *(f32x4*)(pp)     = p0;
        *(f32x4*)(pp + 4) = p1;
        *(f32x4*)(pp + 8) = p2;
    }
}

// Combine k-splits, apply gating/relu/astro/bias/relu. Blocks over o (4 per block).
__global__ void finalize_kernel(const float* __restrict__ P,
                                const float* __restrict__ gates,
                                const float* __restrict__ bias,
                                const float* __restrict__ ws_mastro,
                                float* __restrict__ out) {
    const int t = threadIdx.x;
    const int b = t & 63;
    const int ol = t >> 6;
    const int o = blockIdx.x * 4 + ol;
    f32x4 v0 = {0.f, 0.f, 0.f, 0.f}, v1 = v0, v2 = v0;
#pragma unroll
    for (int ks = 0; ks < KSPLIT; ++ks) {
        const f32x4* p = (const f32x4*)(P + (((size_t)ks * On + o) * Bn + b) * SLOT);
        v0 += p[0]; v1 += p[1]; v2 += p[2];
    }
    float d[12];
#pragma unroll
    for (int j = 0; j < 4; ++j) { d[j] = v0[j]; d[4 + j] = v1[j]; d[8 + j] = v2[j]; }
    float dend = 0.0f;
#pragma unroll
    for (int s = 0; s < Sn; ++s) {
        float g = 1.0f / (1.0f + expf(-gates[o * Sn + s]));
        float r = d[s] > 0.0f ? d[s] : 0.0f;
        dend += r * g;
    }
    float val = d[10] * ws_mastro[o] + bias[o] + dend;
    out[(size_t)b * On + o] = val > 0.0f ? val : 0.0f;
}

extern "C" void kernel_launch(void* const* d_in, const int* in_sizes, int n_in,
                              void* d_out, int out_size, void* d_ws, size_t ws_size,
                              hipStream_t stream) {
    (void)in_sizes; (void)n_in; (void)out_size; (void)ws_size;
    const float* x    = (const float*)d_in[0];
    const float* ctx  = (const float*)d_in[1];
    // d_in[2] prev_activation: unused by the reference
    const float* wgt  = (const float*)d_in[3];
    const float* bias = (const float*)d_in[4];
    const float* aact = (const float*)d_in[5];
    const float* athr = (const float*)d_in[6];
    const float* seg  = (const float*)d_in[7];
    const float* gat  = (const float*)d_in[8];
    const float* cst  = (const float*)d_in[9];
    const float* prn  = (const float*)d_in[10];
    float* out = (float*)d_out;

    float* ws_ctx = (float*)d_ws;                                        // 64 f32
    unsigned short* ws_xbf = (unsigned short*)((char*)d_ws + 256);       // 64x2048 bf16
    float* ws_mastro = (float*)((char*)d_ws + 262400);                   // 2048 f32
    float* ws_P = (float*)((char*)d_ws + 270592);                        // 4*2048*64*12 f32 (~25 MB)

    prep_kernel<<<Bn + (Bn * In) / 256, 256, 0, stream>>>(x, ctx, ws_ctx, ws_xbf);
    mastro_kernel<<<On / 256, 256, 0, stream>>>(aact, athr, ws_ctx, ws_mastro);
    main_kernel<<<(On / 4) * KSPLIT, 64, 0, stream>>>(ws_xbf, wgt, cst, seg, prn, ws_P);
    finalize_kernel<<<On / 4, 256, 0, stream>>>(ws_P, gat, bias, ws_mastro, out);
}